// Round 1
// baseline (5442.286 us; speedup 1.0000x reference)
//
#include <hip/hip_runtime.h>
#include <cmath>

// Problem constants (B,T,C,H from reference)
#define BB 2
#define TT 2048
#define CC 1024
#define HH 16
#define DD 64

// ---------------------------------------------------------------------------
// LayerNorm: one block (256 threads) per row of C=1024 elements.
// ---------------------------------------------------------------------------
__global__ __launch_bounds__(256) void ln_kernel(const float* __restrict__ x,
                                                 const float* __restrict__ w,
                                                 const float* __restrict__ b,
                                                 float* __restrict__ out) {
    const int row = blockIdx.x;           // 0 .. B*T-1
    const int tid = threadIdx.x;
    const float* xr = x + (size_t)row * CC;
    float* orow = out + (size_t)row * CC;

    __shared__ float red[256];

    float v[4];
#pragma unroll
    for (int i = 0; i < 4; ++i) v[i] = xr[tid + i * 256];

    float s = v[0] + v[1] + v[2] + v[3];
    red[tid] = s;
    __syncthreads();
    for (int off = 128; off > 0; off >>= 1) {
        if (tid < off) red[tid] += red[tid + off];
        __syncthreads();
    }
    const float mean = red[0] * (1.0f / CC);
    __syncthreads();

    float d[4];
    float sq = 0.f;
#pragma unroll
    for (int i = 0; i < 4; ++i) {
        d[i] = v[i] - mean;
        sq += d[i] * d[i];
    }
    red[tid] = sq;
    __syncthreads();
    for (int off = 128; off > 0; off >>= 1) {
        if (tid < off) red[tid] += red[tid + off];
        __syncthreads();
    }
    const float var = red[0] * (1.0f / CC);
    const float rstd = rsqrtf(var + 1e-5f);

#pragma unroll
    for (int i = 0; i < 4; ++i) {
        int c = tid + i * 256;
        orow[c] = d[i] * rstd * w[c] + b[c];
    }
}

// ---------------------------------------------------------------------------
// Generic fp32 GEMM: out[M,N] = epilogue(A[M,K] @ W[K,N] + bias[N] [+ res]).
// Tile 64x64x16, 256 threads, 4x4 micro-tile per thread.
// EPI: 0 = bias only, 1 = bias+GELU(exact), 2 = bias+residual add.
// All of M,N % 64 == 0 and K % 16 == 0 for our shapes.
// ---------------------------------------------------------------------------
#define BM 64
#define BN 64
#define BK 16

__device__ __forceinline__ float gelu_exact(float v) {
    return 0.5f * v * (1.0f + erff(v * 0.70710678118654752440f));
}

template <int EPI>
__global__ __launch_bounds__(256) void gemm_kernel(const float* __restrict__ A,
                                                   const float* __restrict__ W,
                                                   const float* __restrict__ bias,
                                                   const float* __restrict__ res,
                                                   float* __restrict__ out,
                                                   int M, int N, int K) {
    __shared__ float As[BK][BM + 4];   // +4 pad: keeps 16B align, breaks bank aliasing
    __shared__ float Ws[BK][BN + 4];

    const int tid = threadIdx.x;
    const int bm = blockIdx.y * BM;
    const int bn = blockIdx.x * BN;
    const int tx = tid & 15;          // 0..15 -> n
    const int ty = tid >> 4;          // 0..15 -> m

    float acc[4][4] = {};

    const int a_row = tid >> 4;       // 0..15, step 16 covers 64 rows
    const int a_col = tid & 15;       // 0..15 within K-tile

    for (int k0 = 0; k0 < K; k0 += BK) {
        // A tile: 64 rows x 16 k, transposed into As[k][m]
#pragma unroll
        for (int r = 0; r < 4; ++r) {
            int m_local = a_row + r * 16;
            As[a_col][m_local] = A[(size_t)(bm + m_local) * K + k0 + a_col];
        }
        // W tile: 16 k x 64 n, row-major
#pragma unroll
        for (int i = 0; i < 4; ++i) {
            int idx = tid + i * 256;
            int r = idx >> 6, c = idx & 63;
            Ws[r][c] = W[(size_t)(k0 + r) * N + bn + c];
        }
        __syncthreads();

#pragma unroll
        for (int kk = 0; kk < BK; ++kk) {
            float4 a4 = *reinterpret_cast<const float4*>(&As[kk][ty * 4]);
            float4 w4 = *reinterpret_cast<const float4*>(&Ws[kk][tx * 4]);
            const float a[4] = {a4.x, a4.y, a4.z, a4.w};
            const float w[4] = {w4.x, w4.y, w4.z, w4.w};
#pragma unroll
            for (int i = 0; i < 4; ++i)
#pragma unroll
                for (int j = 0; j < 4; ++j) acc[i][j] += a[i] * w[j];
        }
        __syncthreads();
    }

#pragma unroll
    for (int i = 0; i < 4; ++i) {
        const int m = bm + ty * 4 + i;
#pragma unroll
        for (int j = 0; j < 4; ++j) {
            const int n = bn + tx * 4 + j;
            float v = acc[i][j] + bias[n];
            if (EPI == 1) v = gelu_exact(v);
            if (EPI == 2) v += res[(size_t)m * N + n];
            out[(size_t)m * N + n] = v;
        }
    }
}

// ---------------------------------------------------------------------------
// Causal attention for one (h, t) row; loops b = 0,1 internally so the
// batch-mean of the softmax probs can be written without atomics.
// qkv layout: [B, T, 3C] with q | k | v, head h at columns h*D .. h*D+63.
// attn_out layout: [B, T, C] (already "transposed back": (b,t,h*D+d)).
// attn_mean layout: [H, T, T].
// ---------------------------------------------------------------------------
__global__ __launch_bounds__(256) void attn_kernel(const float* __restrict__ qkv,
                                                   float* __restrict__ attn_mean,
                                                   float* __restrict__ attn_out) {
    const int t = blockIdx.x;
    const int h = blockIdx.y;
    const int tid = threadIdx.x;
    const int TC3 = 3 * CC;

    __shared__ float p0[TT];
    __shared__ float p1[TT];
    __shared__ float qsh[DD];
    __shared__ float red[256];

    for (int b = 0; b < 2; ++b) {
        float* p = (b == 0) ? p0 : p1;
        const float* base = qkv + (size_t)b * TT * TC3;

        if (tid < DD) qsh[tid] = base[(size_t)t * TC3 + h * DD + tid] * 0.125f; // 1/sqrt(64)
        __syncthreads();

        // scores for s <= t
        float lmax = -INFINITY;
        for (int s = tid; s <= t; s += 256) {
            const float* kr = base + (size_t)s * TC3 + CC + h * DD;
            float dot = 0.f;
#pragma unroll
            for (int i = 0; i < DD; ++i) dot += qsh[i] * kr[i];
            p[s] = dot;
            lmax = fmaxf(lmax, dot);
        }
        red[tid] = lmax;
        __syncthreads();
        for (int off = 128; off > 0; off >>= 1) {
            if (tid < off) red[tid] = fmaxf(red[tid], red[tid + off]);
            __syncthreads();
        }
        const float mx = red[0];
        __syncthreads();

        float lsum = 0.f;
        for (int s = tid; s <= t; s += 256) {
            float e = expf(p[s] - mx);
            p[s] = e;
            lsum += e;
        }
        red[tid] = lsum;
        __syncthreads();
        for (int off = 128; off > 0; off >>= 1) {
            if (tid < off) red[tid] += red[tid + off];
            __syncthreads();
        }
        const float inv = 1.0f / red[0];
        __syncthreads();

        for (int s = tid; s <= t; s += 256) p[s] *= inv;
        __syncthreads();

        // PV: thread (d, g) accumulates over s = g, g+4, ...
        const int d = tid & 63;
        const int g = tid >> 6;
        float accv = 0.f;
        for (int s = g; s <= t; s += 4) {
            accv += p[s] * base[(size_t)s * TC3 + 2 * CC + h * DD + d];
        }
        red[tid] = accv;
        __syncthreads();
        if (tid < 64) {
            float o = red[tid] + red[tid + 64] + red[tid + 128] + red[tid + 192];
            attn_out[((size_t)b * TT + t) * CC + h * DD + tid] = o;
        }
        __syncthreads();
    }

    // batch-mean row, zero the masked tail (d_out is poisoned)
    float* mrow = attn_mean + ((size_t)h * TT + t) * TT;
    for (int s = tid; s < TT; s += 256) {
        mrow[s] = (s <= t) ? 0.5f * (p0[s] + p1[s]) : 0.0f;
    }
}

// ---------------------------------------------------------------------------
extern "C" void kernel_launch(void* const* d_in, const int* in_sizes, int n_in,
                              void* d_out, int out_size, void* d_ws, size_t ws_size,
                              hipStream_t stream) {
    const float* x      = (const float*)d_in[0];
    const float* ln1_w  = (const float*)d_in[1];
    const float* ln1_b  = (const float*)d_in[2];
    const float* w_qkv  = (const float*)d_in[3];
    const float* b_qkv  = (const float*)d_in[4];
    const float* w_proj = (const float*)d_in[5];
    const float* b_proj = (const float*)d_in[6];
    const float* ln2_w  = (const float*)d_in[7];
    const float* ln2_b  = (const float*)d_in[8];
    const float* w_fc   = (const float*)d_in[9];
    const float* b_fc   = (const float*)d_in[10];
    const float* w_fc2  = (const float*)d_in[11];
    const float* b_fc2  = (const float*)d_in[12];

    float* out_x    = (float*)d_out;                            // [B,T,C]
    float* out_attn = (float*)d_out + (size_t)BB * TT * CC;     // [H,T,T]

    float* ws    = (float*)d_ws;
    float* h_ln  = ws;                                          // [B*T, C]      4.19M
    float* qkv   = h_ln + (size_t)BB * TT * CC;                 // [B*T, 3C]    12.58M
    float* att_o = qkv + (size_t)BB * TT * 3 * CC;              // [B*T, C]      4.19M
    float* x1    = att_o + (size_t)BB * TT * CC;                // [B*T, C]      4.19M
    float* h2    = x1 + (size_t)BB * TT * CC;                   // [B*T, 4C]    16.78M

    const int M = BB * TT;   // 4096

    // 1. LN1
    ln_kernel<<<M, 256, 0, stream>>>(x, ln1_w, ln1_b, h_ln);
    // 2. QKV = h_ln @ w_qkv + b_qkv        [4096, 3072]
    gemm_kernel<0><<<dim3(3 * CC / BN, M / BM), 256, 0, stream>>>(
        h_ln, w_qkv, b_qkv, nullptr, qkv, M, 3 * CC, CC);
    // 3. causal attention + batch-mean probs
    attn_kernel<<<dim3(TT, HH), 256, 0, stream>>>(qkv, out_attn, att_o);
    // 4. x1 = x + att_o @ w_proj + b_proj  [4096, 1024]
    gemm_kernel<2><<<dim3(CC / BN, M / BM), 256, 0, stream>>>(
        att_o, w_proj, b_proj, x, x1, M, CC, CC);
    // 5. LN2
    ln_kernel<<<M, 256, 0, stream>>>(x1, ln2_w, ln2_b, h_ln);
    // 6. h2 = gelu(h_ln @ w_fc + b_fc)     [4096, 4096]
    gemm_kernel<1><<<dim3(4 * CC / BN, M / BM), 256, 0, stream>>>(
        h_ln, w_fc, b_fc, nullptr, h2, M, 4 * CC, CC);
    // 7. out_x = x1 + h2 @ w_fc2 + b_fc2   [4096, 1024]
    gemm_kernel<2><<<dim3(CC / BN, M / BM), 256, 0, stream>>>(
        h2, w_fc2, b_fc2, x1, out_x, M, CC, 4 * CC);
}

// Round 2
// 2995.980 us; speedup vs baseline: 1.8165x; 1.8165x over previous
//
#include <hip/hip_runtime.h>
#include <cmath>

// Problem constants (B,T,C,H from reference)
#define BB 2
#define TT 2048
#define CC 1024
#define HH 16
#define DD 64

// ---------------------------------------------------------------------------
// LayerNorm: one block (256 threads) per row of C=1024 elements.
// ---------------------------------------------------------------------------
__global__ __launch_bounds__(256) void ln_kernel(const float* __restrict__ x,
                                                 const float* __restrict__ w,
                                                 const float* __restrict__ b,
                                                 float* __restrict__ out) {
    const int row = blockIdx.x;           // 0 .. B*T-1
    const int tid = threadIdx.x;
    const float* xr = x + (size_t)row * CC;
    float* orow = out + (size_t)row * CC;

    __shared__ float red[256];

    float v[4];
#pragma unroll
    for (int i = 0; i < 4; ++i) v[i] = xr[tid + i * 256];

    float s = v[0] + v[1] + v[2] + v[3];
    red[tid] = s;
    __syncthreads();
    for (int off = 128; off > 0; off >>= 1) {
        if (tid < off) red[tid] += red[tid + off];
        __syncthreads();
    }
    const float mean = red[0] * (1.0f / CC);
    __syncthreads();

    float d[4];
    float sq = 0.f;
#pragma unroll
    for (int i = 0; i < 4; ++i) {
        d[i] = v[i] - mean;
        sq += d[i] * d[i];
    }
    red[tid] = sq;
    __syncthreads();
    for (int off = 128; off > 0; off >>= 1) {
        if (tid < off) red[tid] += red[tid + off];
        __syncthreads();
    }
    const float var = red[0] * (1.0f / CC);
    const float rstd = rsqrtf(var + 1e-5f);

#pragma unroll
    for (int i = 0; i < 4; ++i) {
        int c = tid + i * 256;
        orow[c] = d[i] * rstd * w[c] + b[c];
    }
}

// ---------------------------------------------------------------------------
// Generic fp32 GEMM: out[M,N] = epilogue(A[M,K] @ W[K,N] + bias[N] [+ res]).
// Tile 64x64x16, 256 threads, 4x4 micro-tile per thread.
// EPI: 0 = bias only, 1 = bias+GELU(exact), 2 = bias+residual add.
// ---------------------------------------------------------------------------
#define BM 64
#define BN 64
#define BK 16

__device__ __forceinline__ float gelu_exact(float v) {
    return 0.5f * v * (1.0f + erff(v * 0.70710678118654752440f));
}

template <int EPI>
__global__ __launch_bounds__(256) void gemm_kernel(const float* __restrict__ A,
                                                   const float* __restrict__ W,
                                                   const float* __restrict__ bias,
                                                   const float* __restrict__ res,
                                                   float* __restrict__ out,
                                                   int M, int N, int K) {
    __shared__ float As[BK][BM + 4];
    __shared__ float Ws[BK][BN + 4];

    const int tid = threadIdx.x;
    const int bm = blockIdx.y * BM;
    const int bn = blockIdx.x * BN;
    const int tx = tid & 15;
    const int ty = tid >> 4;

    float acc[4][4] = {};

    const int a_row = tid >> 4;
    const int a_col = tid & 15;

    for (int k0 = 0; k0 < K; k0 += BK) {
#pragma unroll
        for (int r = 0; r < 4; ++r) {
            int m_local = a_row + r * 16;
            As[a_col][m_local] = A[(size_t)(bm + m_local) * K + k0 + a_col];
        }
#pragma unroll
        for (int i = 0; i < 4; ++i) {
            int idx = tid + i * 256;
            int r = idx >> 6, c = idx & 63;
            Ws[r][c] = W[(size_t)(k0 + r) * N + bn + c];
        }
        __syncthreads();

#pragma unroll
        for (int kk = 0; kk < BK; ++kk) {
            float4 a4 = *reinterpret_cast<const float4*>(&As[kk][ty * 4]);
            float4 w4 = *reinterpret_cast<const float4*>(&Ws[kk][tx * 4]);
            const float a[4] = {a4.x, a4.y, a4.z, a4.w};
            const float w[4] = {w4.x, w4.y, w4.z, w4.w};
#pragma unroll
            for (int i = 0; i < 4; ++i)
#pragma unroll
                for (int j = 0; j < 4; ++j) acc[i][j] += a[i] * w[j];
        }
        __syncthreads();
    }

#pragma unroll
    for (int i = 0; i < 4; ++i) {
        const int m = bm + ty * 4 + i;
#pragma unroll
        for (int j = 0; j < 4; ++j) {
            const int n = bn + tx * 4 + j;
            float v = acc[i][j] + bias[n];
            if (EPI == 1) v = gelu_exact(v);
            if (EPI == 2) v += res[(size_t)m * N + n];
            out[(size_t)m * N + n] = v;
        }
    }
}

// ---------------------------------------------------------------------------
// Tiled two-pass causal attention.
// One block per (h, 64-row t-tile), both batch elements handled inside the
// block (so the batch-mean of probs needs no atomics). 64x64 tiles, 4x4
// micro-tile per thread, fp32 register GEMMs from LDS.
// Pass A: online (m,l) per row per b.  Pass B: recompute scores, write
// normalized probs (mean over b) + accumulate PV for both b.
// Block-id swizzle pairs tile tt with 31-tt on the same CU (all 512 blocks
// are co-resident at 2 blocks/CU) to balance the causal triangle.
// ---------------------------------------------------------------------------
__global__ __launch_bounds__(256) void attn_kernel(const float* __restrict__ qkv,
                                                   float* __restrict__ attn_mean,
                                                   float* __restrict__ attn_out) {
    const int lid = blockIdx.x;          // 0..511
    const int u = lid & 255;
    const int h = u & 15;
    const int ta = u >> 4;               // 0..15
    const int tt = (lid < 256) ? ta : 31 - ta;
    const int t0 = tt * 64;

    const int tid = threadIdx.x;
    const int tx = tid & 15;
    const int ty = tid >> 4;
    const size_t TC3 = 3 * CC;

    __shared__ float Qs[2][64][68];
    __shared__ float KV[64][68];
    __shared__ float Ps[64][68];
    __shared__ float mA[2][64];
    __shared__ float lA[2][64];
    __shared__ float red[64][17];

    // load both Q tiles, pre-scaled by 1/sqrt(D)
#pragma unroll
    for (int b = 0; b < 2; ++b) {
        const float* qb = qkv + (size_t)b * TT * TC3 + (size_t)t0 * TC3 + h * DD;
#pragma unroll
        for (int i = 0; i < 4; ++i) {
            int e = tid + i * 256;
            int r = e >> 4, c4 = (e & 15) * 4;
            float4 v = *reinterpret_cast<const float4*>(qb + (size_t)r * TC3 + c4);
            v.x *= 0.125f; v.y *= 0.125f; v.z *= 0.125f; v.w *= 0.125f;
            *reinterpret_cast<float4*>(&Qs[b][r][c4]) = v;
        }
    }
    if (tid < 128) {
        mA[tid >> 6][tid & 63] = -INFINITY;
        lA[tid >> 6][tid & 63] = 0.0f;
    }

    auto load_kv = [&](int b, int s0, int co) {
#pragma unroll
        for (int i = 0; i < 4; ++i) {
            int e = tid + i * 256;
            int r = e >> 4, c4 = (e & 15) * 4;
            *reinterpret_cast<float4*>(&KV[r][c4]) = *reinterpret_cast<const float4*>(
                qkv + (size_t)b * TT * TC3 + (size_t)(s0 + r) * TC3 + co + h * DD + c4);
        }
    };

    auto qk = [&](int b, float (&s)[4][4]) {
#pragma unroll
        for (int i = 0; i < 4; ++i)
#pragma unroll
            for (int j = 0; j < 4; ++j) s[i][j] = 0.f;
        for (int k = 0; k < 64; k += 4) {
            float4 a[4], kk[4];
#pragma unroll
            for (int i = 0; i < 4; ++i) a[i] = *reinterpret_cast<const float4*>(&Qs[b][ty * 4 + i][k]);
#pragma unroll
            for (int j = 0; j < 4; ++j) kk[j] = *reinterpret_cast<const float4*>(&KV[tx * 4 + j][k]);
#pragma unroll
            for (int i = 0; i < 4; ++i)
#pragma unroll
                for (int j = 0; j < 4; ++j)
                    s[i][j] += a[i].x * kk[j].x + a[i].y * kk[j].y + a[i].z * kk[j].z + a[i].w * kk[j].w;
        }
    };

    auto pv = [&](float (&O)[4][4]) {
        for (int s4 = 0; s4 < 64; s4 += 4) {
            float4 pr[4], vr[4];
#pragma unroll
            for (int i = 0; i < 4; ++i) pr[i] = *reinterpret_cast<const float4*>(&Ps[ty * 4 + i][s4]);
#pragma unroll
            for (int ss = 0; ss < 4; ++ss) vr[ss] = *reinterpret_cast<const float4*>(&KV[s4 + ss][tx * 4]);
#pragma unroll
            for (int i = 0; i < 4; ++i) {
                O[i][0] += pr[i].x * vr[0].x + pr[i].y * vr[1].x + pr[i].z * vr[2].x + pr[i].w * vr[3].x;
                O[i][1] += pr[i].x * vr[0].y + pr[i].y * vr[1].y + pr[i].z * vr[2].y + pr[i].w * vr[3].y;
                O[i][2] += pr[i].x * vr[0].z + pr[i].y * vr[1].z + pr[i].z * vr[2].z + pr[i].w * vr[3].z;
                O[i][3] += pr[i].x * vr[0].w + pr[i].y * vr[1].w + pr[i].z * vr[2].w + pr[i].w * vr[3].w;
            }
        }
    };

    // ---------------- Pass A: online (m, l) ----------------
    for (int b = 0; b < 2; ++b) {
        for (int st = 0; st <= tt; ++st) {
            __syncthreads();
            load_kv(b, st * 64, CC);
            __syncthreads();
            float s[4][4];
            qk(b, s);
            if (st == tt) {
#pragma unroll
                for (int i = 0; i < 4; ++i)
#pragma unroll
                    for (int j = 0; j < 4; ++j)
                        if (st * 64 + tx * 4 + j > t0 + ty * 4 + i) s[i][j] = -INFINITY;
            }
#pragma unroll
            for (int i = 0; i < 4; ++i) {
                float lm = fmaxf(fmaxf(s[i][0], s[i][1]), fmaxf(s[i][2], s[i][3]));
                red[ty * 4 + i][tx] = lm;
            }
            __syncthreads();
            float m_old_r = 0.f, m_new_r = 0.f;
            if (tid < 64) {
                float tm = -INFINITY;
#pragma unroll
                for (int k = 0; k < 16; ++k) tm = fmaxf(tm, red[tid][k]);
                m_old_r = mA[b][tid];
                m_new_r = fmaxf(m_old_r, tm);
                mA[b][tid] = m_new_r;
            }
            __syncthreads();
#pragma unroll
            for (int i = 0; i < 4; ++i) {
                float mrow = mA[b][ty * 4 + i];
                float es = expf(s[i][0] - mrow) + expf(s[i][1] - mrow) +
                           expf(s[i][2] - mrow) + expf(s[i][3] - mrow);
                red[ty * 4 + i][tx] = es;
            }
            __syncthreads();
            if (tid < 64) {
                float ts = 0.f;
#pragma unroll
                for (int k = 0; k < 16; ++k) ts += red[tid][k];
                lA[b][tid] = lA[b][tid] * expf(m_old_r - m_new_r) + ts;
            }
        }
    }
    __syncthreads();
    if (tid < 128) {
        int b = tid >> 6, r = tid & 63;
        lA[b][r] = 1.0f / lA[b][r];   // now holds 1/l
    }

    // ---------------- Pass B: probs + PV ----------------
    float O0[4][4] = {}, O1[4][4] = {};
    for (int st = 0; st <= tt; ++st) {
        const int s0 = st * 64;
        // --- b = 0 ---
        __syncthreads();
        load_kv(0, s0, CC);
        __syncthreads();
        float s[4][4];
        qk(0, s);
        float p[4][4];
#pragma unroll
        for (int i = 0; i < 4; ++i) {
            const int trow = t0 + ty * 4 + i;
            const float mrow = mA[0][ty * 4 + i];
            const float inv = lA[0][ty * 4 + i];
#pragma unroll
            for (int j = 0; j < 4; ++j) {
                const int scol = s0 + tx * 4 + j;
                p[i][j] = (st == tt && scol > trow) ? 0.f : expf(s[i][j] - mrow) * inv;
            }
        }
#pragma unroll
        for (int i = 0; i < 4; ++i)
            *reinterpret_cast<float4*>(&Ps[ty * 4 + i][tx * 4]) =
                make_float4(p[i][0], p[i][1], p[i][2], p[i][3]);
        __syncthreads();
        load_kv(0, s0, 2 * CC);
        __syncthreads();
        pv(O0);
        // --- b = 1 ---
        __syncthreads();
        load_kv(1, s0, CC);
        __syncthreads();
        qk(1, s);
#pragma unroll
        for (int i = 0; i < 4; ++i) {
            const int trow = t0 + ty * 4 + i;
            const float mrow = mA[1][ty * 4 + i];
            const float inv = lA[1][ty * 4 + i];
#pragma unroll
            for (int j = 0; j < 4; ++j) {
                const int scol = s0 + tx * 4 + j;
                p[i][j] = (st == tt && scol > trow) ? 0.f : expf(s[i][j] - mrow) * inv;
            }
        }
        // mean = 0.5*(p0 + p1); p0 frag is exactly what this thread wrote to Ps
#pragma unroll
        for (int i = 0; i < 4; ++i) {
            float4 p0v = *reinterpret_cast<const float4*>(&Ps[ty * 4 + i][tx * 4]);
            float4 mv = make_float4(0.5f * (p[i][0] + p0v.x), 0.5f * (p[i][1] + p0v.y),
                                    0.5f * (p[i][2] + p0v.z), 0.5f * (p[i][3] + p0v.w));
            const int trow = t0 + ty * 4 + i;
            *reinterpret_cast<float4*>(attn_mean + ((size_t)h * TT + trow) * TT + s0 + tx * 4) = mv;
        }
        // overwrite Ps with p1 (each thread re-reads only its own cells above)
        __syncthreads();
#pragma unroll
        for (int i = 0; i < 4; ++i)
            *reinterpret_cast<float4*>(&Ps[ty * 4 + i][tx * 4]) =
                make_float4(p[i][0], p[i][1], p[i][2], p[i][3]);
        __syncthreads();
        load_kv(1, s0, 2 * CC);
        __syncthreads();
        pv(O1);
    }

    // ---------------- epilogue ----------------
#pragma unroll
    for (int i = 0; i < 4; ++i) {
        const int trow = t0 + ty * 4 + i;
        *reinterpret_cast<float4*>(attn_out + ((size_t)0 * TT + trow) * CC + h * DD + tx * 4) =
            make_float4(O0[i][0], O0[i][1], O0[i][2], O0[i][3]);
        *reinterpret_cast<float4*>(attn_out + ((size_t)1 * TT + trow) * CC + h * DD + tx * 4) =
            make_float4(O1[i][0], O1[i][1], O1[i][2], O1[i][3]);
    }
    // zero the masked tail of the mean rows (d_out is poisoned)
    const int c0 = (tt + 1) * 64;
    const float4 z4 = make_float4(0.f, 0.f, 0.f, 0.f);
    for (int r = 0; r < 64; ++r) {
        float* row = attn_mean + ((size_t)h * TT + t0 + r) * TT;
        for (int c = c0 + tid * 4; c < TT; c += 1024)
            *reinterpret_cast<float4*>(row + c) = z4;
    }
}

// ---------------------------------------------------------------------------
extern "C" void kernel_launch(void* const* d_in, const int* in_sizes, int n_in,
                              void* d_out, int out_size, void* d_ws, size_t ws_size,
                              hipStream_t stream) {
    const float* x      = (const float*)d_in[0];
    const float* ln1_w  = (const float*)d_in[1];
    const float* ln1_b  = (const float*)d_in[2];
    const float* w_qkv  = (const float*)d_in[3];
    const float* b_qkv  = (const float*)d_in[4];
    const float* w_proj = (const float*)d_in[5];
    const float* b_proj = (const float*)d_in[6];
    const float* ln2_w  = (const float*)d_in[7];
    const float* ln2_b  = (const float*)d_in[8];
    const float* w_fc   = (const float*)d_in[9];
    const float* b_fc   = (const float*)d_in[10];
    const float* w_fc2  = (const float*)d_in[11];
    const float* b_fc2  = (const float*)d_in[12];

    float* out_x    = (float*)d_out;                            // [B,T,C]
    float* out_attn = (float*)d_out + (size_t)BB * TT * CC;     // [H,T,T]

    float* ws    = (float*)d_ws;
    float* h_ln  = ws;                                          // [B*T, C]
    float* qkv   = h_ln + (size_t)BB * TT * CC;                 // [B*T, 3C]
    float* att_o = qkv + (size_t)BB * TT * 3 * CC;              // [B*T, C]
    float* x1    = att_o + (size_t)BB * TT * CC;                // [B*T, C]
    float* h2    = x1 + (size_t)BB * TT * CC;                   // [B*T, 4C]

    const int M = BB * TT;   // 4096

    ln_kernel<<<M, 256, 0, stream>>>(x, ln1_w, ln1_b, h_ln);
    gemm_kernel<0><<<dim3(3 * CC / BN, M / BM), 256, 0, stream>>>(
        h_ln, w_qkv, b_qkv, nullptr, qkv, M, 3 * CC, CC);
    attn_kernel<<<512, 256, 0, stream>>>(qkv, out_attn, att_o);
    gemm_kernel<2><<<dim3(CC / BN, M / BM), 256, 0, stream>>>(
        att_o, w_proj, b_proj, x, x1, M, CC, CC);
    ln_kernel<<<M, 256, 0, stream>>>(x1, ln2_w, ln2_b, h_ln);
    gemm_kernel<1><<<dim3(4 * CC / BN, M / BM), 256, 0, stream>>>(
        h_ln, w_fc, b_fc, nullptr, h2, M, 4 * CC, CC);
    gemm_kernel<2><<<dim3(CC / BN, M / BM), 256, 0, stream>>>(
        h2, w_fc2, b_fc2, x1, out_x, M, CC, 4 * CC);
}

// Round 3
// 1738.356 us; speedup vs baseline: 3.1307x; 1.7235x over previous
//
#include <hip/hip_runtime.h>
#include <cmath>

// Problem constants
#define BB 2
#define TT 2048
#define CC 1024
#define HH 16
#define DD 64

typedef unsigned short u16;
typedef __attribute__((ext_vector_type(8))) short bf16x8;   // 8 bf16 = 4 VGPRs
typedef __attribute__((ext_vector_type(4))) float f32x4;

__device__ __forceinline__ u16 f2bf(float f) {
    union { float f; unsigned u; } v; v.f = f;
    return (u16)((v.u + 0x7fff + ((v.u >> 16) & 1)) >> 16);   // RNE
}

__device__ __forceinline__ float gelu_exact(float v) {
    return 0.5f * v * (1.0f + erff(v * 0.70710678118654752440f));
}

__device__ __forceinline__ void glds16(const void* g, void* l) {
    __builtin_amdgcn_global_load_lds(
        (const __attribute__((address_space(1))) void*)g,
        (__attribute__((address_space(3))) void*)l, 16, 0, 0);
}

// ---------------------------------------------------------------------------
// Weight convert + transpose: W [K,N] fp32 -> WT [N,K] bf16. 64x64 tiles.
// grid = (N/64, K/64), 256 threads.
// ---------------------------------------------------------------------------
__global__ __launch_bounds__(256) void wcvt_kernel(const float* __restrict__ W,
                                                   u16* __restrict__ WT,
                                                   int K, int N) {
    __shared__ u16 t[64][65];
    const int n0 = blockIdx.x * 64, k0 = blockIdx.y * 64;
    const int tid = threadIdx.x;
    const int c = tid & 63;
#pragma unroll
    for (int it = 0; it < 16; ++it) {
        int r = it * 4 + (tid >> 6);
        t[c][r] = f2bf(W[(size_t)(k0 + r) * N + n0 + c]);
    }
    __syncthreads();
#pragma unroll
    for (int it = 0; it < 16; ++it) {
        int r = it * 4 + (tid >> 6);
        WT[(size_t)(n0 + r) * K + k0 + c] = t[r][c];
    }
}

// ---------------------------------------------------------------------------
// LayerNorm: fp32 in, bf16 out. One block per row of C=1024.
// ---------------------------------------------------------------------------
__global__ __launch_bounds__(256) void ln_kernel(const float* __restrict__ x,
                                                 const float* __restrict__ w,
                                                 const float* __restrict__ b,
                                                 u16* __restrict__ out) {
    const int row = blockIdx.x;
    const int tid = threadIdx.x;
    const float* xr = x + (size_t)row * CC;
    u16* orow = out + (size_t)row * CC;

    __shared__ float red[256];

    float v[4];
#pragma unroll
    for (int i = 0; i < 4; ++i) v[i] = xr[tid + i * 256];

    red[tid] = v[0] + v[1] + v[2] + v[3];
    __syncthreads();
    for (int off = 128; off > 0; off >>= 1) {
        if (tid < off) red[tid] += red[tid + off];
        __syncthreads();
    }
    const float mean = red[0] * (1.0f / CC);
    __syncthreads();

    float d[4], sq = 0.f;
#pragma unroll
    for (int i = 0; i < 4; ++i) { d[i] = v[i] - mean; sq += d[i] * d[i]; }
    red[tid] = sq;
    __syncthreads();
    for (int off = 128; off > 0; off >>= 1) {
        if (tid < off) red[tid] += red[tid + off];
        __syncthreads();
    }
    const float rstd = rsqrtf(red[0] * (1.0f / CC) + 1e-5f);

#pragma unroll
    for (int i = 0; i < 4; ++i) {
        int c = tid + i * 256;
        orow[c] = f2bf(d[i] * rstd * w[c] + b[c]);
    }
}

// ---------------------------------------------------------------------------
// bf16 MFMA GEMM (m97 structure): out[M,N] = epi(A[M,K] @ BT[N,K]^T + bias).
// TK=32, 256 threads = 4 waves at (WM x WN), each wave FI x FJ frags of
// 16x16x32. TM = WM*FI*16, TN = WN*FJ*16. global_load_lds width-16 staging.
// EPI: 0=bias, 1=bias+GELU, 2=bias+residual. OUTBF: 1 = store bf16.
// ---------------------------------------------------------------------------
template <int EPI, int OUTBF, int WM, int WN, int FI, int FJ>
__global__ __launch_bounds__(256) void gemm_mfma(const u16* __restrict__ A,
                                                 const u16* __restrict__ BT,
                                                 const float* __restrict__ bias,
                                                 const float* __restrict__ res,
                                                 void* __restrict__ out,
                                                 int M, int N, int K) {
    constexpr int TM = WM * FI * 16;
    constexpr int TN = WN * FJ * 16;
    __shared__ u16 As[TM * 32];
    __shared__ u16 Bs[TN * 32];

    const int tid = threadIdx.x;
    const int lane = tid & 63;
    const int w = tid >> 6;                 // wave 0..3
    const int wr = w / WN, wc = w % WN;
    const int m16 = lane & 15;
    const int quad = lane >> 4;

    const int bm = blockIdx.y * TM;
    const int bn = blockIdx.x * TN;

    f32x4 acc[FI][FJ] = {};

    for (int k0 = 0; k0 < K; k0 += 32) {
        // stage A tile (TM x 32) and B tile (TN x 32), 16B per lane
#pragma unroll
        for (int it = 0; it < TM / 64; ++it) {
            int cb = w * (TM / 64) * 64 + it * 64;     // wave-uniform chunk base
            int q = cb + lane;
            glds16(&A[(size_t)(bm + (q >> 2)) * K + k0 + (q & 3) * 8], &As[cb * 8]);
        }
#pragma unroll
        for (int it = 0; it < TN / 64; ++it) {
            int cb = w * (TN / 64) * 64 + it * 64;
            int q = cb + lane;
            glds16(&BT[(size_t)(bn + (q >> 2)) * K + k0 + (q & 3) * 8], &Bs[cb * 8]);
        }
        __syncthreads();

        bf16x8 a[FI], b[FJ];
#pragma unroll
        for (int i = 0; i < FI; ++i)
            a[i] = *(const bf16x8*)&As[(wr * FI * 16 + 16 * i + m16) * 32 + quad * 8];
#pragma unroll
        for (int j = 0; j < FJ; ++j)
            b[j] = *(const bf16x8*)&Bs[(wc * FJ * 16 + 16 * j + m16) * 32 + quad * 8];
#pragma unroll
        for (int i = 0; i < FI; ++i)
#pragma unroll
            for (int j = 0; j < FJ; ++j)
                acc[i][j] = __builtin_amdgcn_mfma_f32_16x16x32_bf16(a[i], b[j], acc[i][j], 0, 0, 0);
        __syncthreads();
    }

    // epilogue: C/D layout col=lane&15, row=quad*4+reg
#pragma unroll
    for (int i = 0; i < FI; ++i) {
        const int row = bm + wr * FI * 16 + 16 * i + quad * 4;
#pragma unroll
        for (int j = 0; j < FJ; ++j) {
            const int col = bn + wc * FJ * 16 + 16 * j + m16;
            const float bv = bias[col];
#pragma unroll
            for (int r = 0; r < 4; ++r) {
                float v = acc[i][j][r] + bv;
                if (EPI == 1) v = gelu_exact(v);
                if (EPI == 2) v += res[(size_t)(row + r) * N + col];
                if (OUTBF) ((u16*)out)[(size_t)(row + r) * N + col] = f2bf(v);
                else ((float*)out)[(size_t)(row + r) * N + col] = v;
            }
        }
    }
}

// ---------------------------------------------------------------------------
// Tiled two-pass causal attention (unchanged from R1 except bf16 att_o out).
// ---------------------------------------------------------------------------
__global__ __launch_bounds__(256) void attn_kernel(const float* __restrict__ qkv,
                                                   float* __restrict__ attn_mean,
                                                   u16* __restrict__ attn_out) {
    const int lid = blockIdx.x;
    const int u = lid & 255;
    const int h = u & 15;
    const int ta = u >> 4;
    const int tt = (lid < 256) ? ta : 31 - ta;
    const int t0 = tt * 64;

    const int tid = threadIdx.x;
    const int tx = tid & 15;
    const int ty = tid >> 4;
    const size_t TC3 = 3 * CC;

    __shared__ float Qs[2][64][68];
    __shared__ float KV[64][68];
    __shared__ float Ps[64][68];
    __shared__ float mA[2][64];
    __shared__ float lA[2][64];
    __shared__ float red[64][17];

#pragma unroll
    for (int b = 0; b < 2; ++b) {
        const float* qb = qkv + (size_t)b * TT * TC3 + (size_t)t0 * TC3 + h * DD;
#pragma unroll
        for (int i = 0; i < 4; ++i) {
            int e = tid + i * 256;
            int r = e >> 4, c4 = (e & 15) * 4;
            float4 v = *reinterpret_cast<const float4*>(qb + (size_t)r * TC3 + c4);
            v.x *= 0.125f; v.y *= 0.125f; v.z *= 0.125f; v.w *= 0.125f;
            *reinterpret_cast<float4*>(&Qs[b][r][c4]) = v;
        }
    }
    if (tid < 128) {
        mA[tid >> 6][tid & 63] = -INFINITY;
        lA[tid >> 6][tid & 63] = 0.0f;
    }

    auto load_kv = [&](int b, int s0, int co) {
#pragma unroll
        for (int i = 0; i < 4; ++i) {
            int e = tid + i * 256;
            int r = e >> 4, c4 = (e & 15) * 4;
            *reinterpret_cast<float4*>(&KV[r][c4]) = *reinterpret_cast<const float4*>(
                qkv + (size_t)b * TT * TC3 + (size_t)(s0 + r) * TC3 + co + h * DD + c4);
        }
    };

    auto qk = [&](int b, float (&s)[4][4]) {
#pragma unroll
        for (int i = 0; i < 4; ++i)
#pragma unroll
            for (int j = 0; j < 4; ++j) s[i][j] = 0.f;
        for (int k = 0; k < 64; k += 4) {
            float4 a[4], kk[4];
#pragma unroll
            for (int i = 0; i < 4; ++i) a[i] = *reinterpret_cast<const float4*>(&Qs[b][ty * 4 + i][k]);
#pragma unroll
            for (int j = 0; j < 4; ++j) kk[j] = *reinterpret_cast<const float4*>(&KV[tx * 4 + j][k]);
#pragma unroll
            for (int i = 0; i < 4; ++i)
#pragma unroll
                for (int j = 0; j < 4; ++j)
                    s[i][j] += a[i].x * kk[j].x + a[i].y * kk[j].y + a[i].z * kk[j].z + a[i].w * kk[j].w;
        }
    };

    auto pv = [&](float (&O)[4][4]) {
        for (int s4 = 0; s4 < 64; s4 += 4) {
            float4 pr[4], vr[4];
#pragma unroll
            for (int i = 0; i < 4; ++i) pr[i] = *reinterpret_cast<const float4*>(&Ps[ty * 4 + i][s4]);
#pragma unroll
            for (int ss = 0; ss < 4; ++ss) vr[ss] = *reinterpret_cast<const float4*>(&KV[s4 + ss][tx * 4]);
#pragma unroll
            for (int i = 0; i < 4; ++i) {
                O[i][0] += pr[i].x * vr[0].x + pr[i].y * vr[1].x + pr[i].z * vr[2].x + pr[i].w * vr[3].x;
                O[i][1] += pr[i].x * vr[0].y + pr[i].y * vr[1].y + pr[i].z * vr[2].y + pr[i].w * vr[3].y;
                O[i][2] += pr[i].x * vr[0].z + pr[i].y * vr[1].z + pr[i].z * vr[2].z + pr[i].w * vr[3].z;
                O[i][3] += pr[i].x * vr[0].w + pr[i].y * vr[1].w + pr[i].z * vr[2].w + pr[i].w * vr[3].w;
            }
        }
    };

    // Pass A
    for (int b = 0; b < 2; ++b) {
        for (int st = 0; st <= tt; ++st) {
            __syncthreads();
            load_kv(b, st * 64, CC);
            __syncthreads();
            float s[4][4];
            qk(b, s);
            if (st == tt) {
#pragma unroll
                for (int i = 0; i < 4; ++i)
#pragma unroll
                    for (int j = 0; j < 4; ++j)
                        if (st * 64 + tx * 4 + j > t0 + ty * 4 + i) s[i][j] = -INFINITY;
            }
#pragma unroll
            for (int i = 0; i < 4; ++i)
                red[ty * 4 + i][tx] = fmaxf(fmaxf(s[i][0], s[i][1]), fmaxf(s[i][2], s[i][3]));
            __syncthreads();
            float m_old_r = 0.f, m_new_r = 0.f;
            if (tid < 64) {
                float tm = -INFINITY;
#pragma unroll
                for (int k = 0; k < 16; ++k) tm = fmaxf(tm, red[tid][k]);
                m_old_r = mA[b][tid];
                m_new_r = fmaxf(m_old_r, tm);
                mA[b][tid] = m_new_r;
            }
            __syncthreads();
#pragma unroll
            for (int i = 0; i < 4; ++i) {
                float mrow = mA[b][ty * 4 + i];
                red[ty * 4 + i][tx] = expf(s[i][0] - mrow) + expf(s[i][1] - mrow) +
                                      expf(s[i][2] - mrow) + expf(s[i][3] - mrow);
            }
            __syncthreads();
            if (tid < 64) {
                float ts = 0.f;
#pragma unroll
                for (int k = 0; k < 16; ++k) ts += red[tid][k];
                lA[b][tid] = lA[b][tid] * expf(m_old_r - m_new_r) + ts;
            }
        }
    }
    __syncthreads();
    if (tid < 128) {
        int b = tid >> 6, r = tid & 63;
        lA[b][r] = 1.0f / lA[b][r];
    }

    // Pass B
    float O0[4][4] = {}, O1[4][4] = {};
    for (int st = 0; st <= tt; ++st) {
        const int s0 = st * 64;
        __syncthreads();
        load_kv(0, s0, CC);
        __syncthreads();
        float s[4][4];
        qk(0, s);
        float p[4][4];
#pragma unroll
        for (int i = 0; i < 4; ++i) {
            const int trow = t0 + ty * 4 + i;
            const float mrow = mA[0][ty * 4 + i];
            const float inv = lA[0][ty * 4 + i];
#pragma unroll
            for (int j = 0; j < 4; ++j) {
                const int scol = s0 + tx * 4 + j;
                p[i][j] = (st == tt && scol > trow) ? 0.f : expf(s[i][j] - mrow) * inv;
            }
        }
#pragma unroll
        for (int i = 0; i < 4; ++i)
            *reinterpret_cast<float4*>(&Ps[ty * 4 + i][tx * 4]) =
                make_float4(p[i][0], p[i][1], p[i][2], p[i][3]);
        __syncthreads();
        load_kv(0, s0, 2 * CC);
        __syncthreads();
        pv(O0);
        __syncthreads();
        load_kv(1, s0, CC);
        __syncthreads();
        qk(1, s);
#pragma unroll
        for (int i = 0; i < 4; ++i) {
            const int trow = t0 + ty * 4 + i;
            const float mrow = mA[1][ty * 4 + i];
            const float inv = lA[1][ty * 4 + i];
#pragma unroll
            for (int j = 0; j < 4; ++j) {
                const int scol = s0 + tx * 4 + j;
                p[i][j] = (st == tt && scol > trow) ? 0.f : expf(s[i][j] - mrow) * inv;
            }
        }
#pragma unroll
        for (int i = 0; i < 4; ++i) {
            float4 p0v = *reinterpret_cast<const float4*>(&Ps[ty * 4 + i][tx * 4]);
            float4 mv = make_float4(0.5f * (p[i][0] + p0v.x), 0.5f * (p[i][1] + p0v.y),
                                    0.5f * (p[i][2] + p0v.z), 0.5f * (p[i][3] + p0v.w));
            const int trow = t0 + ty * 4 + i;
            *reinterpret_cast<float4*>(attn_mean + ((size_t)h * TT + trow) * TT + s0 + tx * 4) = mv;
        }
        __syncthreads();
#pragma unroll
        for (int i = 0; i < 4; ++i)
            *reinterpret_cast<float4*>(&Ps[ty * 4 + i][tx * 4]) =
                make_float4(p[i][0], p[i][1], p[i][2], p[i][3]);
        __syncthreads();
        load_kv(1, s0, 2 * CC);
        __syncthreads();
        pv(O1);
    }

    // epilogue (bf16 att_o)
#pragma unroll
    for (int i = 0; i < 4; ++i) {
        const int trow = t0 + ty * 4 + i;
        *reinterpret_cast<ushort4*>(attn_out + ((size_t)0 * TT + trow) * CC + h * DD + tx * 4) =
            make_ushort4(f2bf(O0[i][0]), f2bf(O0[i][1]), f2bf(O0[i][2]), f2bf(O0[i][3]));
        *reinterpret_cast<ushort4*>(attn_out + ((size_t)1 * TT + trow) * CC + h * DD + tx * 4) =
            make_ushort4(f2bf(O1[i][0]), f2bf(O1[i][1]), f2bf(O1[i][2]), f2bf(O1[i][3]));
    }
    const int c0 = (tt + 1) * 64;
    const float4 z4 = make_float4(0.f, 0.f, 0.f, 0.f);
    for (int r = 0; r < 64; ++r) {
        float* row = attn_mean + ((size_t)h * TT + t0 + r) * TT;
        for (int c = c0 + tid * 4; c < TT; c += 1024)
            *reinterpret_cast<float4*>(row + c) = z4;
    }
}

// ---------------------------------------------------------------------------
extern "C" void kernel_launch(void* const* d_in, const int* in_sizes, int n_in,
                              void* d_out, int out_size, void* d_ws, size_t ws_size,
                              hipStream_t stream) {
    const float* x      = (const float*)d_in[0];
    const float* ln1_w  = (const float*)d_in[1];
    const float* ln1_b  = (const float*)d_in[2];
    const float* w_qkv  = (const float*)d_in[3];
    const float* b_qkv  = (const float*)d_in[4];
    const float* w_proj = (const float*)d_in[5];
    const float* b_proj = (const float*)d_in[6];
    const float* ln2_w  = (const float*)d_in[7];
    const float* ln2_b  = (const float*)d_in[8];
    const float* w_fc   = (const float*)d_in[9];
    const float* b_fc   = (const float*)d_in[10];
    const float* w_fc2  = (const float*)d_in[11];
    const float* b_fc2  = (const float*)d_in[12];

    float* out_x    = (float*)d_out;
    float* out_attn = out_x + (size_t)BB * TT * CC;

    char* wp = (char*)d_ws;
    u16* wT_qkv = (u16*)wp;  wp += (size_t)3072 * 1024 * 2;
    u16* wT_proj = (u16*)wp; wp += (size_t)1024 * 1024 * 2;
    u16* wT_fc  = (u16*)wp;  wp += (size_t)4096 * 1024 * 2;
    u16* wT_fc2 = (u16*)wp;  wp += (size_t)1024 * 4096 * 2;
    u16* h_ln   = (u16*)wp;  wp += (size_t)4096 * 1024 * 2;
    u16* att_o  = (u16*)wp;  wp += (size_t)4096 * 1024 * 2;
    u16* h2     = (u16*)wp;  wp += (size_t)4096 * 4096 * 2;
    float* qkv  = (float*)wp; wp += (size_t)4096 * 3072 * 4;
    float* x1   = (float*)wp; wp += (size_t)4096 * 1024 * 4;

    const int M = BB * TT;   // 4096

    // weight convert+transpose (bf16, [N,K])
    wcvt_kernel<<<dim3(3072 / 64, 1024 / 64), 256, 0, stream>>>(w_qkv, wT_qkv, 1024, 3072);
    wcvt_kernel<<<dim3(1024 / 64, 1024 / 64), 256, 0, stream>>>(w_proj, wT_proj, 1024, 1024);
    wcvt_kernel<<<dim3(4096 / 64, 1024 / 64), 256, 0, stream>>>(w_fc, wT_fc, 1024, 4096);
    wcvt_kernel<<<dim3(1024 / 64, 4096 / 64), 256, 0, stream>>>(w_fc2, wT_fc2, 4096, 1024);

    // 1. LN1 -> bf16
    ln_kernel<<<M, 256, 0, stream>>>(x, ln1_w, ln1_b, h_ln);
    // 2. qkv = h_ln @ w_qkv + b_qkv  [4096,3072] fp32  (128x128 tiles)
    gemm_mfma<0, 0, 2, 2, 4, 4><<<dim3(3072 / 128, M / 128), 256, 0, stream>>>(
        h_ln, wT_qkv, b_qkv, nullptr, qkv, M, 3072, 1024);
    // 3. attention (fp32 in, bf16 att_o out)
    attn_kernel<<<512, 256, 0, stream>>>(qkv, out_attn, att_o);
    // 4. x1 = x + att_o @ w_proj + b_proj  [4096,1024] fp32  (128x64 tiles)
    gemm_mfma<2, 0, 4, 1, 2, 4><<<dim3(1024 / 64, M / 128), 256, 0, stream>>>(
        att_o, wT_proj, b_proj, x, x1, M, 1024, 1024);
    // 5. LN2 -> bf16
    ln_kernel<<<M, 256, 0, stream>>>(x1, ln2_w, ln2_b, h_ln);
    // 6. h2 = gelu(h_ln @ w_fc + b_fc)  [4096,4096] bf16  (128x128 tiles)
    gemm_mfma<1, 1, 2, 2, 4, 4><<<dim3(4096 / 128, M / 128), 256, 0, stream>>>(
        h_ln, wT_fc, b_fc, nullptr, h2, M, 4096, 1024);
    // 7. out_x = x1 + h2 @ w_fc2 + b_fc2  [4096,1024] fp32  (128x64 tiles)
    gemm_mfma<2, 0, 4, 1, 2, 4><<<dim3(1024 / 64, M / 128), 256, 0, stream>>>(
        h2, wT_fc2, b_fc2, x1, out_x, M, 1024, 4096);
}